// Round 1
// baseline (234.904 us; speedup 1.0000x reference)
//
#include <hip/hip_runtime.h>
#include <hip/hip_bf16.h>

#define N_NODES 16000
#define N_EDGES 80000
#define N_GRAPHS 64
#define NBASIS 10
#define MAX_RADIUS 6.0f

// folded constants
#define SILU_NORM 1.679177f
#define SMOOTH_C (1.14136f * 7.38905609893065f)   // 1.14136*e^2
#define SQRT10 3.16227766016838f
#define INV_SQRT10 0.316227766016838f
#define SQRT3 1.7320508075688772f
#define QK_NORM 0.04419417382415922f              // 1/sqrt(2*16*16)
#define SCALE_B 0.02209708691207961f              // (1/8)*(1/sqrt(32))
#define RSTEP (11.0f / 6.0f)                      // 1/step
#define STEP (6.0f / 11.0f)

__device__ __forceinline__ float sus(float x) {
    return x > 0.0f ? expf(-1.0f / x) : 0.0f;
}

// h[32] = SILU_NORM * silu(basis @ W1 / sqrt(10))
__device__ __forceinline__ void compute_h(float len, const float* __restrict__ W1, float* h) {
    float basis[NBASIS];
#pragma unroll
    for (int i = 0; i < NBASIS; ++i) {
        float d = (len - STEP * (float)(i + 1)) * RSTEP;
        basis[i] = SMOOTH_C * sus(d + 1.0f) * sus(1.0f - d) * SQRT10;
    }
#pragma unroll
    for (int m = 0; m < 32; ++m) {
        float s = 0.0f;
#pragma unroll
        for (int i = 0; i < NBASIS; ++i) s += basis[i] * W1[i * 32 + m];
        s *= INV_SQRT10;
        float sig = 1.0f / (1.0f + expf(-s));
        h[m] = SILU_NORM * s * sig;
    }
}

// One block per (element, mol) combo: build per-combo contraction tables.
__global__ void table_kernel(const float* __restrict__ z_table,
                             const float* __restrict__ mol_table,
                             const float* __restrict__ Wq,
                             const float* __restrict__ W2k,
                             const float* __restrict__ W2v,
                             const float* __restrict__ Wa,
                             float* __restrict__ Bk, float* __restrict__ Bv0,
                             float* __restrict__ Bv1, float* __restrict__ qa) {
    int combo = blockIdx.x;      // 0..199
    int elem = combo >> 1;
    int mol = combo & 1;
    __shared__ float feat[64];
    __shared__ float q0[16];
    int tid = threadIdx.x;       // 256 threads
    if (tid < 48) feat[tid] = z_table[elem * 48 + tid];
    else if (tid < 64) feat[tid] = mol_table[mol * 16 + (tid - 48)];
    __syncthreads();
    if (tid < 16) {
        float s = 0.0f;
        for (int u = 0; u < 64; ++u) s += feat[u] * Wq[u * 16 + tid];
        q0[tid] = s * 0.125f;    // / sqrt(NODE_DIM)
    }
    __syncthreads();
    if (tid < 16) {
        float s = 0.0f;
        for (int u = 0; u < 16; ++u) s += q0[u] * Wa[u * 16 + tid];
        qa[combo * 16 + tid] = s * QK_NORM;
    }
    for (int o = tid; o < 512; o += 256) {
        int m = o >> 4, w = o & 15;
        float sk = 0.0f, sv0 = 0.0f, sv1 = 0.0f;
        for (int u = 0; u < 64; ++u) {
            float f = feat[u];
            sk  += f * W2k[m * 2048 + u * 16 + w];
            sv0 += f * W2v[m * 2048 + u * 16 + w];
            sv1 += f * W2v[m * 2048 + 1024 + u * 16 + w];
        }
        Bk [combo * 512 + o] = sk  * SCALE_B;
        Bv0[combo * 512 + o] = sv0 * SCALE_B;
        Bv1[combo * 512 + o] = sv1 * SCALE_B;
    }
}

// Pass 1: per edge, compute expv = cutoff*exp(qk) and accumulate z[dst].
// 16 lanes per edge; lane = k-channel w.
__global__ void edge_pass1(const float* __restrict__ pos,
                           const int* __restrict__ xarr, const int* __restrict__ molid,
                           const int* __restrict__ esrc, const int* __restrict__ edst,
                           const float* __restrict__ W1k,
                           const float* __restrict__ Bk, const float* __restrict__ qa,
                           float* __restrict__ expv, float* __restrict__ zbuf) {
    int tid = threadIdx.x;
    int lane = tid & 15;
    int e = blockIdx.x * 16 + (tid >> 4);
    if (e >= N_EDGES) return;
    int src = esrc[e], dst = edst[e];
    float vx = pos[src * 3 + 0] - pos[dst * 3 + 0];
    float vy = pos[src * 3 + 1] - pos[dst * 3 + 1];
    float vz = pos[src * 3 + 2] - pos[dst * 3 + 2];
    float len = sqrtf(vx * vx + vy * vy + vz * vz);
    float h[32];
    compute_h(len, W1k, h);
    int cs = xarr[src] * 2 + molid[src];
    int cd = xarr[dst] * 2 + molid[dst];
    const float* B = Bk + cs * 512 + lane;
    float k0 = 0.0f;
#pragma unroll
    for (int m = 0; m < 32; ++m) k0 += h[m] * B[m * 16];
    float p = qa[cd * 16 + lane] * k0;
#pragma unroll
    for (int off = 1; off < 16; off <<= 1) p += __shfl_xor(p, off, 64);
    if (lane == 0) {
        float cutoff = sus(10.0f * (1.0f - len * (1.0f / 6.0f)));
        float ev = cutoff * expf(p);
        expv[e] = ev;
        atomicAdd(&zbuf[dst], ev);
    }
}

// Pass 2: per edge, att = sqrt(expv/z), accumulate att*v into out_node[dst].
__global__ void edge_pass2(const float* __restrict__ pos,
                           const int* __restrict__ xarr, const int* __restrict__ molid,
                           const int* __restrict__ esrc, const int* __restrict__ edst,
                           const float* __restrict__ W1v,
                           const float* __restrict__ Bv0, const float* __restrict__ Bv1,
                           const float* __restrict__ expv, const float* __restrict__ zbuf,
                           float* __restrict__ out_node) {
    int tid = threadIdx.x;
    int lane = tid & 15;
    int e = blockIdx.x * 16 + (tid >> 4);
    if (e >= N_EDGES) return;
    int src = esrc[e], dst = edst[e];
    float vx = pos[src * 3 + 0] - pos[dst * 3 + 0];
    float vy = pos[src * 3 + 1] - pos[dst * 3 + 1];
    float vz = pos[src * 3 + 2] - pos[dst * 3 + 2];
    float len = sqrtf(vx * vx + vy * vy + vz * vz);
    float h[32];
    compute_h(len, W1v, h);
    int cs = xarr[src] * 2 + molid[src];
    const float* B0 = Bv0 + cs * 512 + lane;
    const float* B1 = Bv1 + cs * 512 + lane;
    float v0 = 0.0f, s1 = 0.0f;
#pragma unroll
    for (int m = 0; m < 32; ++m) {
        v0 += h[m] * B0[m * 16];
        s1 += h[m] * B1[m * 16];
    }
    float zz = zbuf[dst];
    if (zz == 0.0f) zz = 1.0f;
    float att = sqrtf(expv[e] / zz);
    float inv_len = 1.0f / len;
    float shx = SQRT3 * vx * inv_len;
    float shy = SQRT3 * vy * inv_len;
    float shz = SQRT3 * vz * inv_len;
    float* on = out_node + (size_t)dst * 64;
    atomicAdd(&on[lane], att * v0);
    float t = att * s1;
    atomicAdd(&on[16 + lane * 3 + 0], t * shx);
    atomicAdd(&on[16 + lane * 3 + 1], t * shy);
    atomicAdd(&on[16 + lane * 3 + 2], t * shz);
}

// Final: one block per graph; batch_idx is sorted -> binary search range.
__global__ void final_kernel(const float* __restrict__ out_node,
                             const int* __restrict__ batch, float* __restrict__ out) {
    int g = blockIdx.x;
    int c = threadIdx.x;   // 64 threads = 64 channels
    int lo = 0, hi = N_NODES;
    while (lo < hi) { int mid = (lo + hi) >> 1; if (batch[mid] < g) lo = mid + 1; else hi = mid; }
    int s = lo;
    lo = s; hi = N_NODES;
    while (lo < hi) { int mid = (lo + hi) >> 1; if (batch[mid] <= g) lo = mid + 1; else hi = mid; }
    int en = lo;
    float sum = 0.0f;
    for (int n = s; n < en; ++n) sum += out_node[(size_t)n * 64 + c];
    float cnt = (float)((en - s) > 0 ? (en - s) : 1);
    out[g * 64 + c] = sum / cnt;
}

extern "C" void kernel_launch(void* const* d_in, const int* in_sizes, int n_in,
                              void* d_out, int out_size, void* d_ws, size_t ws_size,
                              hipStream_t stream) {
    const float* pos       = (const float*)d_in[0];
    const float* z_table   = (const float*)d_in[1];
    const float* mol_table = (const float*)d_in[2];
    const float* Wq        = (const float*)d_in[3];
    const float* W1k       = (const float*)d_in[4];
    const float* W2k       = (const float*)d_in[5];
    const float* W1v       = (const float*)d_in[6];
    const float* W2v       = (const float*)d_in[7];
    const float* Wa        = (const float*)d_in[8];
    // d_in[9] = Wb: unused (q1 == 0 in the reference)
    const int* x     = (const int*)d_in[10];
    const int* molid = (const int*)d_in[11];
    const int* esrc  = (const int*)d_in[12];
    const int* edst  = (const int*)d_in[13];
    const int* batch = (const int*)d_in[14];
    float* out = (float*)d_out;

    float* ws = (float*)d_ws;
    float* Bk       = ws;                  // 200*512
    float* Bv0      = Bk  + 200 * 512;     // 200*512
    float* Bv1      = Bv0 + 200 * 512;     // 200*512
    float* qa       = Bv1 + 200 * 512;     // 200*16
    float* zbuf     = qa  + 200 * 16;      // 16000
    float* expv     = zbuf + N_NODES;      // 80000
    float* out_node = expv + N_EDGES;      // 16000*64

    hipMemsetAsync(zbuf, 0, N_NODES * sizeof(float), stream);
    hipMemsetAsync(out_node, 0, (size_t)N_NODES * 64 * sizeof(float), stream);

    table_kernel<<<200, 256, 0, stream>>>(z_table, mol_table, Wq, W2k, W2v, Wa,
                                          Bk, Bv0, Bv1, qa);
    edge_pass1<<<N_EDGES / 16, 256, 0, stream>>>(pos, x, molid, esrc, edst,
                                                 W1k, Bk, qa, expv, zbuf);
    edge_pass2<<<N_EDGES / 16, 256, 0, stream>>>(pos, x, molid, esrc, edst,
                                                 W1v, Bv0, Bv1, expv, zbuf, out_node);
    final_kernel<<<N_GRAPHS, 64, 0, stream>>>(out_node, batch, out);
}

// Round 2
// 186.967 us; speedup vs baseline: 1.2564x; 1.2564x over previous
//
#include <hip/hip_runtime.h>
#include <hip/hip_bf16.h>

#define N_NODES 16000
#define N_EDGES 80000
#define N_GRAPHS 64
#define NBASIS 10

#define SILU_NORM 1.679177f
#define SMOOTH_C (1.14136f * 7.38905609893065f)   // 1.14136*e^2
#define SQRT10 3.16227766016838f
#define INV_SQRT10 0.316227766016838f
#define SQRT3 1.7320508075688772f
#define QK_NORM 0.04419417382415922f              // 1/sqrt(2*16*16)
#define SCALE_B 0.02209708691207961f              // (1/8)*(1/sqrt(32))
#define RSTEP (11.0f / 6.0f)
#define STEP (6.0f / 11.0f)
#define NACC 128                                  // blocks in accumulate pass

__device__ __forceinline__ float sus_f(float x) {
    return x > 0.0f ? __expf(-1.0f / x) : 0.0f;
}

// One block per (element, mol) combo: build per-combo contraction tables,
// TRANSPOSED to [combo][w][m] so edge kernels read float4 rows.
__global__ void table_kernel(const float* __restrict__ z_table,
                             const float* __restrict__ mol_table,
                             const float* __restrict__ Wq,
                             const float* __restrict__ W2k,
                             const float* __restrict__ W2v,
                             const float* __restrict__ Wa,
                             float* __restrict__ BkT, float* __restrict__ Bv0T,
                             float* __restrict__ Bv1T, float* __restrict__ qa) {
    int combo = blockIdx.x;      // 0..199
    int elem = combo >> 1;
    int mol = combo & 1;
    __shared__ float feat[64];
    __shared__ float q0[16];
    int tid = threadIdx.x;       // 256 threads
    if (tid < 48) feat[tid] = z_table[elem * 48 + tid];
    else if (tid < 64) feat[tid] = mol_table[mol * 16 + (tid - 48)];
    __syncthreads();
    if (tid < 16) {
        float s = 0.0f;
        for (int u = 0; u < 64; ++u) s += feat[u] * Wq[u * 16 + tid];
        q0[tid] = s * 0.125f;    // / sqrt(NODE_DIM)
    }
    __syncthreads();
    if (tid < 16) {
        float s = 0.0f;
        for (int u = 0; u < 16; ++u) s += q0[u] * Wa[u * 16 + tid];
        qa[combo * 16 + tid] = s * QK_NORM;
    }
    for (int o = tid; o < 512; o += 256) {
        int m = o >> 4, w = o & 15;
        float sk = 0.0f, sv0 = 0.0f, sv1 = 0.0f;
        for (int u = 0; u < 64; ++u) {
            float f = feat[u];
            sk  += f * W2k[m * 2048 + u * 16 + w];
            sv0 += f * W2v[m * 2048 + u * 16 + w];
            sv1 += f * W2v[m * 2048 + 1024 + u * 16 + w];
        }
        int to = combo * 512 + w * 32 + m;   // transposed
        BkT [to] = sk  * SCALE_B;
        Bv0T[to] = sv0 * SCALE_B;
        Bv1T[to] = sv1 * SCALE_B;
    }
}

// Edge pass: 16 lanes/edge. Lane l owns basis[l] (l<10) and MLP channels
// {l, l+16}; broadcasts via __shfl width=16. Computes expv, accumulates z,
// stores per-edge geometry+combo for the accumulate pass.
__global__ void edge_kernel(const float* __restrict__ pos,
                            const int* __restrict__ xarr, const int* __restrict__ molid,
                            const int* __restrict__ esrc, const int* __restrict__ edst,
                            const float* __restrict__ W1k,
                            const float* __restrict__ BkT, const float* __restrict__ qa,
                            float4* __restrict__ geom4, float* __restrict__ expvbuf,
                            int* __restrict__ csbuf, float* __restrict__ zbuf) {
    int tid = threadIdx.x;
    int lane = tid & 15;
    int e = blockIdx.x * 16 + (tid >> 4);   // 80000 = 5000*16, all valid
    int src = esrc[e], dst = edst[e];
    float vx = pos[src * 3 + 0] - pos[dst * 3 + 0];
    float vy = pos[src * 3 + 1] - pos[dst * 3 + 1];
    float vz = pos[src * 3 + 2] - pos[dst * 3 + 2];
    float len = sqrtf(vx * vx + vy * vy + vz * vz);

    // basis: lane i (<10) computes basis[i], then broadcast
    float myb = 0.0f;
    {
        float d = (len - STEP * (float)(lane + 1)) * RSTEP;
        if (lane < 10) myb = SMOOTH_C * sus_f(d + 1.0f) * sus_f(1.0f - d) * SQRT10;
    }
    float b[10];
#pragma unroll
    for (int i = 0; i < 10; ++i) b[i] = __shfl(myb, i, 16);

    // h_k for owned channels m=lane, lane+16
    float hk0, hk1;
    {
        float s0 = 0.0f, s1 = 0.0f;
#pragma unroll
        for (int i = 0; i < 10; ++i) {
            s0 += b[i] * W1k[i * 32 + lane];
            s1 += b[i] * W1k[i * 32 + lane + 16];
        }
        s0 *= INV_SQRT10; s1 *= INV_SQRT10;
        hk0 = SILU_NORM * s0 / (1.0f + __expf(-s0));
        hk1 = SILU_NORM * s1 / (1.0f + __expf(-s1));
    }
    int cs = xarr[src] * 2 + molid[src];
    int cd = xarr[dst] * 2 + molid[dst];

    // k0[lane] = sum_m hk[m] * BkT[cs][lane][m]  (float4 rows)
    const float4* bk = (const float4*)(BkT + cs * 512 + lane * 32);
    float k0 = 0.0f;
#pragma unroll
    for (int mq = 0; mq < 8; ++mq) {
        float4 a = bk[mq];
#pragma unroll
        for (int r = 0; r < 4; ++r) {
            int m = mq * 4 + r;
            float hm = __shfl((m < 16) ? hk0 : hk1, m & 15, 16);
            k0 += hm * ((const float*)&a)[r];
        }
    }
    float p = qa[cd * 16 + lane] * k0;
#pragma unroll
    for (int off = 1; off < 16; off <<= 1) p += __shfl_xor(p, off, 16);

    float cutoff = sus_f(10.0f * (1.0f - len * (1.0f / 6.0f)));
    float ev = cutoff * __expf(p);
    if (lane == 0) {
        atomicAdd(&zbuf[dst], ev);
        float il = SQRT3 / len;
        geom4[e] = make_float4(vx * il, vy * il, vz * il, len);
        expvbuf[e] = ev;
        csbuf[e] = cs;
    }
}

// Accumulate pass: recompute v-MLP per edge (cheap, lane-split), weight by
// att, accumulate into per-graph LDS table, write per-block partials.
__global__ void acc_kernel(const int* __restrict__ edst, const int* __restrict__ batch,
                           const float* __restrict__ W1v,
                           const float* __restrict__ Bv0T, const float* __restrict__ Bv1T,
                           const float4* __restrict__ geom4, const float* __restrict__ expvbuf,
                           const int* __restrict__ csbuf, const float* __restrict__ zbuf,
                           float* __restrict__ partial) {
    __shared__ float acc[N_GRAPHS * 64];
    int tid = threadIdx.x;
    int lane = tid & 15;
    for (int i = tid; i < N_GRAPHS * 64; i += 256) acc[i] = 0.0f;
    __syncthreads();
    int gid = blockIdx.x * 16 + (tid >> 4);   // 0..NACC*16-1
    for (int e = gid; e < N_EDGES; e += NACC * 16) {
        float4 g4 = geom4[e];
        float len = g4.w;
        int dst = edst[e];
        int cs = csbuf[e];
        float z = zbuf[dst];
        if (z == 0.0f) z = 1.0f;
        float att = sqrtf(expvbuf[e] / z);
        int g = batch[dst];

        float myb = 0.0f;
        {
            float d = (len - STEP * (float)(lane + 1)) * RSTEP;
            if (lane < 10) myb = SMOOTH_C * sus_f(d + 1.0f) * sus_f(1.0f - d) * SQRT10;
        }
        float b[10];
#pragma unroll
        for (int i = 0; i < 10; ++i) b[i] = __shfl(myb, i, 16);
        float hv0, hv1;
        {
            float s0 = 0.0f, s1 = 0.0f;
#pragma unroll
            for (int i = 0; i < 10; ++i) {
                s0 += b[i] * W1v[i * 32 + lane];
                s1 += b[i] * W1v[i * 32 + lane + 16];
            }
            s0 *= INV_SQRT10; s1 *= INV_SQRT10;
            hv0 = SILU_NORM * s0 / (1.0f + __expf(-s0));
            hv1 = SILU_NORM * s1 / (1.0f + __expf(-s1));
        }
        const float4* b0 = (const float4*)(Bv0T + cs * 512 + lane * 32);
        const float4* b1 = (const float4*)(Bv1T + cs * 512 + lane * 32);
        float v0 = 0.0f, s1v = 0.0f;
#pragma unroll
        for (int mq = 0; mq < 8; ++mq) {
            float4 a0 = b0[mq];
            float4 a1 = b1[mq];
#pragma unroll
            for (int r = 0; r < 4; ++r) {
                int m = mq * 4 + r;
                float hm = __shfl((m < 16) ? hv0 : hv1, m & 15, 16);
                v0  += hm * ((const float*)&a0)[r];
                s1v += hm * ((const float*)&a1)[r];
            }
        }
        v0 *= att;
        s1v *= att;
        float* row = &acc[g * 64];
        atomicAdd(&row[lane], v0);
        atomicAdd(&row[16 + lane * 3 + 0], s1v * g4.x);
        atomicAdd(&row[16 + lane * 3 + 1], s1v * g4.y);
        atomicAdd(&row[16 + lane * 3 + 2], s1v * g4.z);
    }
    __syncthreads();
    for (int i = tid; i < N_GRAPHS * 64; i += 256)
        partial[blockIdx.x * (N_GRAPHS * 64) + i] = acc[i];
}

// Reduce partials + divide by per-graph node count (batch is sorted).
__global__ void reduce_kernel(const float* __restrict__ partial,
                              const int* __restrict__ batch,
                              float* __restrict__ out) {
    int g = blockIdx.x;
    int c = threadIdx.x;   // 64 channels
    float s = 0.0f;
    for (int bb = 0; bb < NACC; ++bb) s += partial[bb * (N_GRAPHS * 64) + g * 64 + c];
    int lo = 0, hi = N_NODES;
    while (lo < hi) { int m = (lo + hi) >> 1; if (batch[m] < g) lo = m + 1; else hi = m; }
    int st = lo;
    lo = st; hi = N_NODES;
    while (lo < hi) { int m = (lo + hi) >> 1; if (batch[m] <= g) lo = m + 1; else hi = m; }
    int cnt = lo - st;
    if (cnt < 1) cnt = 1;
    out[g * 64 + c] = s / (float)cnt;
}

extern "C" void kernel_launch(void* const* d_in, const int* in_sizes, int n_in,
                              void* d_out, int out_size, void* d_ws, size_t ws_size,
                              hipStream_t stream) {
    const float* pos       = (const float*)d_in[0];
    const float* z_table   = (const float*)d_in[1];
    const float* mol_table = (const float*)d_in[2];
    const float* Wq        = (const float*)d_in[3];
    const float* W1k       = (const float*)d_in[4];
    const float* W2k       = (const float*)d_in[5];
    const float* W1v       = (const float*)d_in[6];
    const float* W2v       = (const float*)d_in[7];
    const float* Wa        = (const float*)d_in[8];
    // d_in[9] = Wb: unused (q1 == 0 in the reference)
    const int* x     = (const int*)d_in[10];
    const int* molid = (const int*)d_in[11];
    const int* esrc  = (const int*)d_in[12];
    const int* edst  = (const int*)d_in[13];
    const int* batch = (const int*)d_in[14];
    float* out = (float*)d_out;

    float* ws = (float*)d_ws;
    float* BkT   = ws;                     // 200*512
    float* Bv0T  = BkT  + 200 * 512;       // 200*512
    float* Bv1T  = Bv0T + 200 * 512;       // 200*512
    float* qa    = Bv1T + 200 * 512;       // 200*16
    float* zbuf  = qa   + 200 * 16;        // 16000
    float4* geom4 = (float4*)(zbuf + N_NODES);       // 80000 float4 (16B aligned: offset 326400 floats)
    float* expvbuf = (float*)(geom4 + N_EDGES);      // 80000
    int*   csbuf   = (int*)(expvbuf + N_EDGES);      // 80000
    float* partial = (float*)(csbuf + N_EDGES);      // NACC*4096

    hipMemsetAsync(zbuf, 0, N_NODES * sizeof(float), stream);

    table_kernel<<<200, 256, 0, stream>>>(z_table, mol_table, Wq, W2k, W2v, Wa,
                                          BkT, Bv0T, Bv1T, qa);
    edge_kernel<<<N_EDGES / 16, 256, 0, stream>>>(pos, x, molid, esrc, edst,
                                                  W1k, BkT, qa,
                                                  geom4, expvbuf, csbuf, zbuf);
    acc_kernel<<<NACC, 256, 0, stream>>>(edst, batch, W1v, Bv0T, Bv1T,
                                         geom4, expvbuf, csbuf, zbuf, partial);
    reduce_kernel<<<N_GRAPHS, 64, 0, stream>>>(partial, batch, out);
}

// Round 3
// 150.192 us; speedup vs baseline: 1.5640x; 1.2449x over previous
//
#include <hip/hip_runtime.h>
#include <hip/hip_bf16.h>

#define N_NODES 16000
#define N_EDGES 80000
#define N_GRAPHS 64
#define NBASIS 10

#define SILU_NORM 1.679177f
#define SMOOTH_C (1.14136f * 7.38905609893065f)   // 1.14136*e^2
#define SQRT10 3.16227766016838f
#define INV_SQRT10 0.316227766016838f
#define SQRT3 1.7320508075688772f
#define QK_NORM 0.04419417382415922f              // 1/sqrt(2*16*16)
#define SCALE_B 0.02209708691207961f              // (1/8)*(1/sqrt(32))
#define RSTEP (11.0f / 6.0f)
#define STEP (6.0f / 11.0f)
#define BC (SMOOTH_C * SQRT10)                    // basis outer constant
#define NACC 256                                  // blocks in accumulate pass

__device__ __forceinline__ float sus_f(float x) {
    return x > 0.0f ? __expf(-__fdividef(1.0f, x)) : 0.0f;
}

// basis[i], fused double-sus: sus(1+d)*sus(1-d) = exp(-1/(1+d)-1/(1-d)) when
// both args > 0, else 0. Fully per-lane, no cross-lane traffic.
__device__ __forceinline__ void basis_regs(float len, float* b) {
#pragma unroll
    for (int i = 0; i < NBASIS; ++i) {
        float d = (len - STEP * (float)(i + 1)) * RSTEP;
        float pd = 1.0f + d, md = 1.0f - d;
        float e = __expf(-(__fdividef(1.0f, pd) + __fdividef(1.0f, md)));
        b[i] = (pd > 0.0f && md > 0.0f) ? BC * e : 0.0f;
    }
}

__device__ __forceinline__ float silu_n(float s) {
    return __fdividef(SILU_NORM * s, 1.0f + __expf(-s));
}

// One block per (element, mol) combo: build per-combo contraction tables,
// TRANSPOSED to [combo][w][m] so edge kernels read float4 rows.
__global__ void table_kernel(const float* __restrict__ z_table,
                             const float* __restrict__ mol_table,
                             const float* __restrict__ Wq,
                             const float* __restrict__ W2k,
                             const float* __restrict__ W2v,
                             const float* __restrict__ Wa,
                             float* __restrict__ BkT, float* __restrict__ Bv0T,
                             float* __restrict__ Bv1T, float* __restrict__ qa) {
    int combo = blockIdx.x;      // 0..199
    int elem = combo >> 1;
    int mol = combo & 1;
    __shared__ float feat[64];
    __shared__ float q0[16];
    int tid = threadIdx.x;       // 256 threads
    if (tid < 48) feat[tid] = z_table[elem * 48 + tid];
    else if (tid < 64) feat[tid] = mol_table[mol * 16 + (tid - 48)];
    __syncthreads();
    if (tid < 16) {
        float s = 0.0f;
        for (int u = 0; u < 64; ++u) s += feat[u] * Wq[u * 16 + tid];
        q0[tid] = s * 0.125f;    // / sqrt(NODE_DIM)
    }
    __syncthreads();
    if (tid < 16) {
        float s = 0.0f;
        for (int u = 0; u < 16; ++u) s += q0[u] * Wa[u * 16 + tid];
        qa[combo * 16 + tid] = s * QK_NORM;
    }
    for (int o = tid; o < 512; o += 256) {
        int m = o >> 4, w = o & 15;
        float sk = 0.0f, sv0 = 0.0f, sv1 = 0.0f;
        for (int u = 0; u < 64; ++u) {
            float f = feat[u];
            sk  += f * W2k[m * 2048 + u * 16 + w];
            sv0 += f * W2v[m * 2048 + u * 16 + w];
            sv1 += f * W2v[m * 2048 + 1024 + u * 16 + w];
        }
        int to = combo * 512 + w * 32 + m;   // transposed
        BkT [to] = sk  * SCALE_B;
        Bv0T[to] = sv0 * SCALE_B;
        Bv1T[to] = sv1 * SCALE_B;
    }
}

// Edge pass: 16 lanes/edge. Basis in registers (fused exp); h staged through
// LDS (2 writes + 8 float4 reads, same-wave so no barrier). Computes expv,
// accumulates z, stores per-edge geometry + packed (cs|g|dst).
__global__ void edge_kernel(const float* __restrict__ pos,
                            const int* __restrict__ xarr, const int* __restrict__ molid,
                            const int* __restrict__ esrc, const int* __restrict__ edst,
                            const int* __restrict__ batch,
                            const float* __restrict__ W1k,
                            const float* __restrict__ BkT, const float* __restrict__ qa,
                            float4* __restrict__ geom4, float* __restrict__ expvbuf,
                            int* __restrict__ pkbuf, float* __restrict__ zbuf) {
    __shared__ float hbuf[16][36];           // 16 groups, padded stride
    int tid = threadIdx.x;
    int lane = tid & 15;
    int grp = tid >> 4;
    int e = blockIdx.x * 16 + grp;           // 80000 = 5000*16, all valid
    int src = esrc[e], dst = edst[e];
    float vx = pos[src * 3 + 0] - pos[dst * 3 + 0];
    float vy = pos[src * 3 + 1] - pos[dst * 3 + 1];
    float vz = pos[src * 3 + 2] - pos[dst * 3 + 2];
    float len = sqrtf(vx * vx + vy * vy + vz * vz);

    float b[NBASIS];
    basis_regs(len, b);

    float s0 = 0.0f, s1 = 0.0f;
#pragma unroll
    for (int i = 0; i < NBASIS; ++i) {
        s0 += b[i] * W1k[i * 32 + lane];
        s1 += b[i] * W1k[i * 32 + lane + 16];
    }
    hbuf[grp][lane]      = silu_n(s0 * INV_SQRT10);
    hbuf[grp][lane + 16] = silu_n(s1 * INV_SQRT10);

    int cs = xarr[src] * 2 + molid[src];
    int cd = xarr[dst] * 2 + molid[dst];
    int g  = batch[dst];

    const float4* hp = (const float4*)&hbuf[grp][0];
    const float4* bk = (const float4*)(BkT + cs * 512 + lane * 32);
    float k0 = 0.0f;
#pragma unroll
    for (int mq = 0; mq < 8; ++mq) {
        float4 h4 = hp[mq];
        float4 a  = bk[mq];
        k0 += h4.x * a.x + h4.y * a.y + h4.z * a.z + h4.w * a.w;
    }
    float p = qa[cd * 16 + lane] * k0;
#pragma unroll
    for (int off = 1; off < 16; off <<= 1) p += __shfl_xor(p, off, 16);

    if (lane == 0) {
        float cutoff = sus_f(10.0f * (1.0f - len * (1.0f / 6.0f)));
        float ev = cutoff * __expf(p);
        atomicAdd(&zbuf[dst], ev);
        float il = SQRT3 / len;
        geom4[e] = make_float4(vx * il, vy * il, vz * il, len);
        expvbuf[e] = ev;
        pkbuf[e] = cs | (g << 8) | (dst << 14);
    }
}

// Accumulate pass: 1024 threads/block, 256 blocks (32 waves/CU). Recompute
// v-MLP per edge, weight by att, accumulate into per-graph LDS table
// (padded stride 68), write per-block partials.
__global__ void __launch_bounds__(1024)
acc_kernel(const float* __restrict__ W1v,
           const float* __restrict__ Bv0T, const float* __restrict__ Bv1T,
           const float4* __restrict__ geom4, const float* __restrict__ expvbuf,
           const int* __restrict__ pkbuf, const float* __restrict__ zbuf,
           float* __restrict__ partial) {
    __shared__ float acc[N_GRAPHS * 68];     // padded rows: 17.4 KB
    __shared__ float hbuf[64][36];           // 64 groups
    int tid = threadIdx.x;
    int lane = tid & 15;
    int grp = tid >> 4;
    for (int i = tid; i < N_GRAPHS * 68; i += 1024) acc[i] = 0.0f;
    __syncthreads();

    // hoist W1v rows for this lane's two channels
    float w1a[NBASIS], w1b[NBASIS];
#pragma unroll
    for (int i = 0; i < NBASIS; ++i) {
        w1a[i] = W1v[i * 32 + lane];
        w1b[i] = W1v[i * 32 + lane + 16];
    }

    int gid = blockIdx.x * 64 + grp;         // group id, 0..NACC*64-1
    for (int e = gid; e < N_EDGES; e += NACC * 64) {
        float4 g4 = geom4[e];
        int pk = pkbuf[e];
        float ev = expvbuf[e];
        int cs = pk & 255;
        int g = (pk >> 8) & 63;
        int dst = pk >> 14;
        float z = zbuf[dst];
        if (z == 0.0f) z = 1.0f;
        float att = sqrtf(__fdividef(ev, z));

        float b[NBASIS];
        basis_regs(g4.w, b);
        float s0 = 0.0f, s1 = 0.0f;
#pragma unroll
        for (int i = 0; i < NBASIS; ++i) {
            s0 += b[i] * w1a[i];
            s1 += b[i] * w1b[i];
        }
        hbuf[grp][lane]      = silu_n(s0 * INV_SQRT10);
        hbuf[grp][lane + 16] = silu_n(s1 * INV_SQRT10);

        const float4* hp = (const float4*)&hbuf[grp][0];
        const float4* b0 = (const float4*)(Bv0T + cs * 512 + lane * 32);
        const float4* b1 = (const float4*)(Bv1T + cs * 512 + lane * 32);
        float v0 = 0.0f, s1v = 0.0f;
#pragma unroll
        for (int mq = 0; mq < 8; ++mq) {
            float4 h4 = hp[mq];
            float4 a0 = b0[mq];
            float4 a1 = b1[mq];
            v0  += h4.x * a0.x + h4.y * a0.y + h4.z * a0.z + h4.w * a0.w;
            s1v += h4.x * a1.x + h4.y * a1.y + h4.z * a1.z + h4.w * a1.w;
        }
        v0 *= att;
        s1v *= att;
        float* row = &acc[g * 68];
        atomicAdd(&row[lane], v0);
        atomicAdd(&row[16 + lane * 3 + 0], s1v * g4.x);
        atomicAdd(&row[16 + lane * 3 + 1], s1v * g4.y);
        atomicAdd(&row[16 + lane * 3 + 2], s1v * g4.z);
    }
    __syncthreads();
    for (int i = tid; i < N_GRAPHS * 64; i += 1024)
        partial[blockIdx.x * (N_GRAPHS * 64) + i] = acc[(i >> 6) * 68 + (i & 63)];
}

// Reduce partials + divide by per-graph node count (batch is sorted).
__global__ void reduce_kernel(const float* __restrict__ partial,
                              const int* __restrict__ batch,
                              float* __restrict__ out) {
    __shared__ float red[4][64];
    int g = blockIdx.x;
    int c = threadIdx.x & 63;
    int q = threadIdx.x >> 6;    // 0..3
    float s = 0.0f;
    for (int bb = q; bb < NACC; bb += 4) s += partial[bb * (N_GRAPHS * 64) + g * 64 + c];
    red[q][c] = s;
    __syncthreads();
    if (q == 0) {
        float tot = red[0][c] + red[1][c] + red[2][c] + red[3][c];
        int lo = 0, hi = N_NODES;
        while (lo < hi) { int m = (lo + hi) >> 1; if (batch[m] < g) lo = m + 1; else hi = m; }
        int st = lo;
        lo = st; hi = N_NODES;
        while (lo < hi) { int m = (lo + hi) >> 1; if (batch[m] <= g) lo = m + 1; else hi = m; }
        int cnt = lo - st;
        if (cnt < 1) cnt = 1;
        out[g * 64 + c] = tot / (float)cnt;
    }
}

extern "C" void kernel_launch(void* const* d_in, const int* in_sizes, int n_in,
                              void* d_out, int out_size, void* d_ws, size_t ws_size,
                              hipStream_t stream) {
    const float* pos       = (const float*)d_in[0];
    const float* z_table   = (const float*)d_in[1];
    const float* mol_table = (const float*)d_in[2];
    const float* Wq        = (const float*)d_in[3];
    const float* W1k       = (const float*)d_in[4];
    const float* W2k       = (const float*)d_in[5];
    const float* W1v       = (const float*)d_in[6];
    const float* W2v       = (const float*)d_in[7];
    const float* Wa        = (const float*)d_in[8];
    // d_in[9] = Wb: unused (q1 == 0 in the reference)
    const int* x     = (const int*)d_in[10];
    const int* molid = (const int*)d_in[11];
    const int* esrc  = (const int*)d_in[12];
    const int* edst  = (const int*)d_in[13];
    const int* batch = (const int*)d_in[14];
    float* out = (float*)d_out;

    float* ws = (float*)d_ws;
    float* BkT   = ws;                     // 200*512
    float* Bv0T  = BkT  + 200 * 512;       // 200*512
    float* Bv1T  = Bv0T + 200 * 512;       // 200*512
    float* qa    = Bv1T + 200 * 512;       // 200*16
    float* zbuf  = qa   + 200 * 16;        // 16000
    float4* geom4 = (float4*)(zbuf + N_NODES);       // 80000 float4 (offset 326400 floats, 16B aligned)
    float* expvbuf = (float*)(geom4 + N_EDGES);      // 80000
    int*   pkbuf   = (int*)(expvbuf + N_EDGES);      // 80000
    float* partial = (float*)(pkbuf + N_EDGES);      // NACC*4096

    hipMemsetAsync(zbuf, 0, N_NODES * sizeof(float), stream);

    table_kernel<<<200, 256, 0, stream>>>(z_table, mol_table, Wq, W2k, W2v, Wa,
                                          BkT, Bv0T, Bv1T, qa);
    edge_kernel<<<N_EDGES / 16, 256, 0, stream>>>(pos, x, molid, esrc, edst, batch,
                                                  W1k, BkT, qa,
                                                  geom4, expvbuf, pkbuf, zbuf);
    acc_kernel<<<NACC, 1024, 0, stream>>>(W1v, Bv0T, Bv1T,
                                          geom4, expvbuf, pkbuf, zbuf, partial);
    reduce_kernel<<<N_GRAPHS, 256, 0, stream>>>(partial, batch, out);
}